// Round 12
// baseline (172.514 us; speedup 1.0000x reference)
//
#include <hip/hip_runtime.h>

#define B_  4
#define S_  1024
#define D_  1024
#define H_  16
#define HD_ 64
#define EPS_ 1e-5f

typedef _Float16 f16x8 __attribute__((ext_vector_type(8)));
typedef _Float16 f16x4 __attribute__((ext_vector_type(4)));
typedef __bf16 bf16x8 __attribute__((ext_vector_type(8)));
typedef float  f32x4  __attribute__((ext_vector_type(4)));
typedef unsigned short ushort4v __attribute__((ext_vector_type(4)));

// async global->LDS, 16B per lane; LDS dest is wave-uniform base + lane*16
#define GLD16(gp, lp) __builtin_amdgcn_global_load_lds( \
    (const __attribute__((address_space(1))) void*)(gp), \
    (__attribute__((address_space(3))) void*)(lp), 16, 0, 0)

// pack two f32 into one u32 of two bf16 (RNE via native cast), low = first
static __device__ __forceinline__ unsigned pk2bf(float a, float b) {
  union { __bf16 h; unsigned short u; } ua, ub;
  ua.h = (__bf16)a; ub.h = (__bf16)b;
  return (unsigned)ua.u | ((unsigned)ub.u << 16);
}

// ---------------------------------------------------------------- convert ---
// R12-VERIFIED verbatim.
__global__ __launch_bounds__(256) void cvt_all(
    const float* __restrict__ x,  _Float16* __restrict__ xh,
    const float* __restrict__ Wq, _Float16* __restrict__ wqh,
    const float* __restrict__ Wk, _Float16* __restrict__ wkh,
    const float* __restrict__ Wv, _Float16* __restrict__ wvh,
    float* __restrict__ Vtail) {
  int bid = blockIdx.x;
  if (bid >= 7168) {                    // 4 blocks zero Vtail (B*H*HD f32)
    int i = (bid - 7168) * 1024 + threadIdx.x * 4;
    *(float4*)(Vtail + i) = make_float4(0.f, 0.f, 0.f, 0.f);
    return;
  }
  const float* src; _Float16* dst; int base;
  if (bid < 4096)      { src = x;  dst = xh;  base = bid; }
  else if (bid < 5120) { src = Wq; dst = wqh; base = bid - 4096; }
  else if (bid < 6144) { src = Wk; dst = wkh; base = bid - 5120; }
  else                 { src = Wv; dst = wvh; base = bid - 6144; }
  int i = base * 1024 + threadIdx.x * 4;
  float4 f = *(const float4*)(src + i);
  f16x4 h;
  h.x = (_Float16)f.x; h.y = (_Float16)f.y; h.z = (_Float16)f.z; h.w = (_Float16)f.w;
  *(f16x4*)(dst + i) = h;
}

// ----------------------------------- GEMM q + fused LN (128x128, 8 waves) ---
// R21: traffic-optimal retile. T = Nt*A + Mt*B with Nt*Mt fixed; halving the
// grid to 256 blocks at Nt=8 (BN=128) cuts staging 192->128 MB (R14 measured
// ~10 TB/s marginal on staged bytes). 512-thread blocks (8 waves = 4M x 2N;
// each wave = 32 rows x one 64-col head -> LN epilogue unchanged per-wave)
// keep waves/CU = 8 and waves/SIMD = 2 identical to the old 2x256t config.
// BK=128 (R19-neutral); with 512 threads each 8KB ks-slab = one GLD16 round.
__global__ __launch_bounds__(512, 1) void gemm_q_ln(
    const _Float16* __restrict__ A,      // xh [4096,1024]
    const _Float16* __restrict__ Bw,     // wqh [1024,1024]
    const float* __restrict__ bias,      // bq
    const float* __restrict__ ln_g, const float* __restrict__ ln_b,
    _Float16* __restrict__ qh,           // raw q  [4096,1024]
    _Float16* __restrict__ Qn)           // LN'd q, head-major [bh,s,64]
{
  __shared__ _Float16 As[4 * 128 * 32];   // 32 KB  [ks][128 rows][32]
  __shared__ _Float16 Bs[4 * 128 * 32];   // 32 KB  [ks][128 rows][32]

  int tid  = threadIdx.x;
  int lane = tid & 63;
  int wave = tid >> 6;                    // 0..7
  int wm = wave >> 1, wn = wave & 1;      // 4 row-bands x 2 col-heads
  int qd = lane >> 4, l15 = lane & 15;

  // ---- XCD-chunked swizzle (flat 0..255, 256%8==0 -> bijective) ----
  int flat = blockIdx.x + 8 * blockIdx.y;
  int swz  = (flat & 7) * 32 + (flat >> 3);
  int bx = swz & 7, by = swz >> 3;        // 8 N-tiles x 32 M-tiles

  long row0 = (long)by * 128;
  long col0 = (long)bx * 128;

  int r_a = tid >> 2;                     // 0..127
  int c_a = (tid & 3) * 8;

  f32x4 acc[2][4] = {};

  for (int kk = 0; kk < D_; kk += 128) {
    for (int ks2 = 0; ks2 < 4; ks2++) {
      GLD16(A  + (row0 + r_a) * D_ + kk + ks2 * 32 + c_a, As + ks2 * 4096 + tid * 8);
      GLD16(Bw + (col0 + r_a) * D_ + kk + ks2 * 32 + c_a, Bs + ks2 * 4096 + tid * 8);
    }
    __syncthreads();

    for (int ks = 0; ks < 4; ks++) {
      f16x8 af[2], bfr[4];
      for (int i = 0; i < 2; i++)
        af[i]  = *(const f16x8*)(As + ks * 4096 + (wm * 32 + i * 16 + l15) * 32 + qd * 8);
      for (int j = 0; j < 4; j++)
        bfr[j] = *(const f16x8*)(Bs + ks * 4096 + (wn * 64 + j * 16 + l15) * 32 + qd * 8);
      for (int i = 0; i < 2; i++)
        for (int j = 0; j < 4; j++)
          acc[i][j] = __builtin_amdgcn_mfma_f32_16x16x32_f16(af[i], bfr[j], acc[i][j], 0, 0, 0);
    }
    __syncthreads();
  }

  // ---- fused epilogue: bias + LN over the 64-col head, dual store ----
  int h = bx * 2 + wn;                      // wave's 64-col strip == head h
  long rw = row0 + wm * 32;                 // wave's first row
  int bb = (int)(rw >> 10);                 // batch
  long bh = (long)bb * H_ + h;
  float gv[4], bl[4], bc[4];
  for (int j = 0; j < 4; j++) {
    int d = j * 16 + l15;
    gv[j] = ln_g[d]; bl[j] = ln_b[d]; bc[j] = bias[h * 64 + d];
  }
  for (int i = 0; i < 2; i++) {
    float m4[4], i4[4];
    for (int r = 0; r < 4; r++) {
      float s = 0.f, q = 0.f;
      for (int j = 0; j < 4; j++) {
        float y = acc[i][j][r] + bc[j];
        s += y; q = fmaf(y, y, q);
      }
      for (int off = 1; off < 16; off <<= 1) {
        s += __shfl_xor(s, off, 64);
        q += __shfl_xor(q, off, 64);
      }
      float m = s * (1.f / 64.f);
      m4[r] = m;
      i4[r] = rsqrtf(q * (1.f / 64.f) - m * m + EPS_);
    }
    for (int r = 0; r < 4; r++) {
      long srow = rw + i * 16 + qd * 4 + r;
      long sloc = srow & (S_ - 1);
      for (int j = 0; j < 4; j++) {
        float y = acc[i][j][r] + bc[j];
        qh[srow * D_ + h * 64 + j * 16 + l15] = (_Float16)y;
        Qn[(bh * S_ + sloc) * HD_ + j * 16 + l15] =
            (_Float16)((y - m4[r]) * i4[r] * gv[j] + bl[j]);
      }
    }
  }
}

// --------------------------------- GEMM k/v + fused LN (256x128, 8 waves) ---
// R21 retile: 256x128 tiles, 512 threads (8 waves = 4M x 2N; wave = 64x64,
// per-wave geometry IDENTICAL to the R12-verified 128x128 kernel). Grid
// (8,16,2) = 256 blocks; staging 256->192 MB. Epilogues R12-verified
// verbatim (h = bx*2+wn, rw = row0 + wm*64 unchanged formulas).
__global__ __launch_bounds__(512, 1) void gemm_kv_ln(
    const _Float16* __restrict__ A,      // qh [4096,1024]
    const _Float16* __restrict__ Bk, const float* __restrict__ bk,
    const _Float16* __restrict__ Bv, const float* __restrict__ bv,
    const float* __restrict__ ln_g, const float* __restrict__ ln_b,
    const int* __restrict__ seq_len,
    _Float16* __restrict__ Kn,           // LN'd k, head-major [bh,s,64]
    unsigned short* __restrict__ Vt,     // LN'd v bf16, transposed [bh,64,S]
    float* __restrict__ Vtail)
{
  __shared__ _Float16 As[4 * 256 * 32];   // 64 KB  [ks][256 rows][32]
  __shared__ _Float16 Bs[4 * 128 * 32];   // 32 KB  [ks][128 rows][32]

  int tid  = threadIdx.x;
  int lane = tid & 63;
  int wave = tid >> 6;                    // 0..7
  int wm = wave >> 1, wn = wave & 1;      // 4 row-bands(64) x 2 col-heads
  int qd = lane >> 4, l15 = lane & 15;

  // ---- XCD-chunked swizzle over flat (bx,by,z), nwg=256, bijective ----
  int flat = blockIdx.x + 8 * blockIdx.y + 128 * blockIdx.z;
  int swz  = (flat & 7) * 32 + (flat >> 3);
  int z    = swz >> 7;
  int rem  = swz & 127;
  int by   = rem >> 3, bx = rem & 7;      // 16 M-tiles x 8 N-tiles

  const _Float16* Bm = z ? Bv : Bk;
  const float* bias  = z ? bv : bk;

  long row0 = (long)by * 256;
  long col0 = (long)bx * 128;

  int r_a = tid >> 2;                     // 0..127
  int c_a = (tid & 3) * 8;

  f32x4 acc[4][4] = {};

  for (int kk = 0; kk < D_; kk += 128) {
    for (int ks2 = 0; ks2 < 4; ks2++) {
      GLD16(A  + (row0 + r_a) * D_ + kk + ks2 * 32 + c_a,       As + ks2 * 8192 + tid * 8);
      GLD16(A  + (row0 + 128 + r_a) * D_ + kk + ks2 * 32 + c_a, As + ks2 * 8192 + 4096 + tid * 8);
      GLD16(Bm + (col0 + r_a) * D_ + kk + ks2 * 32 + c_a,       Bs + ks2 * 4096 + tid * 8);
    }
    __syncthreads();

    for (int ks = 0; ks < 4; ks++) {
      f16x8 af[4], bfr[4];
      for (int t = 0; t < 4; t++) {
        af[t]  = *(const f16x8*)(As + ks * 8192 + (wm * 64 + t * 16 + l15) * 32 + qd * 8);
        bfr[t] = *(const f16x8*)(Bs + ks * 4096 + (wn * 64 + t * 16 + l15) * 32 + qd * 8);
      }
      for (int i = 0; i < 4; i++)
        for (int j = 0; j < 4; j++)
          acc[i][j] = __builtin_amdgcn_mfma_f32_16x16x32_f16(af[i], bfr[j], acc[i][j], 0, 0, 0);
    }
    __syncthreads();
  }

  // ---- fused epilogue (R12-verified formulas) ----
  int h = bx * 2 + wn;                      // wave's 64-col strip == head h
  long rw = row0 + wm * 64;                 // wave's first row
  int bb = (int)(rw >> 10);
  long bh = (long)bb * H_ + h;
  float gv[4], bl[4], bc[4];
  for (int j = 0; j < 4; j++) {
    int d = j * 16 + l15;
    gv[j] = ln_g[d]; bl[j] = ln_b[d]; bc[j] = bias[h * 64 + d];
  }

  if (z == 0) {
    // ---- k: LN -> f16 Kn head-major ----
    for (int i = 0; i < 4; i++) {
      float m4[4], i4[4];
      for (int r = 0; r < 4; r++) {
        float s = 0.f, q = 0.f;
        for (int j = 0; j < 4; j++) {
          float y = acc[i][j][r] + bc[j];
          s += y; q = fmaf(y, y, q);
        }
        for (int off = 1; off < 16; off <<= 1) {
          s += __shfl_xor(s, off, 64);
          q += __shfl_xor(q, off, 64);
        }
        float m = s * (1.f / 64.f);
        m4[r] = m;
        i4[r] = rsqrtf(q * (1.f / 64.f) - m * m + EPS_);
      }
      for (int r = 0; r < 4; r++) {
        long sloc = (rw + i * 16 + qd * 4 + r) & (S_ - 1);
        for (int j = 0; j < 4; j++) {
          float y = acc[i][j][r] + bc[j];
          Kn[(bh * S_ + sloc) * HD_ + j * 16 + l15] =
              (_Float16)((y - m4[r]) * i4[r] * gv[j] + bl[j]);
        }
      }
    }
  } else {
    // ---- v: LN -> bf16 Vt transposed + Vtail tail sums ----
    int len = seq_len[bb];
    float tsum[4] = {0.f, 0.f, 0.f, 0.f};
    for (int i = 0; i < 4; i++) {
      float m4[4], i4[4];
      for (int r = 0; r < 4; r++) {
        float s = 0.f, q = 0.f;
        for (int j = 0; j < 4; j++) {
          float y = acc[i][j][r] + bc[j];
          s += y; q = fmaf(y, y, q);
        }
        for (int off = 1; off < 16; off <<= 1) {
          s += __shfl_xor(s, off, 64);
          q += __shfl_xor(q, off, 64);
        }
        float m = s * (1.f / 64.f);
        m4[r] = m;
        i4[r] = rsqrtf(q * (1.f / 64.f) - m * m + EPS_);
      }
      int s0loc = (int)((rw + i * 16 + qd * 4) & (S_ - 1));
      for (int j = 0; j < 4; j++) {
        ushort4v w;
        for (int r = 0; r < 4; r++) {
          float y = acc[i][j][r] + bc[j];
          float vo = (y - m4[r]) * i4[r] * gv[j] + bl[j];
          __bf16 vb = (__bf16)vo;
          union { __bf16 hh; unsigned short uu; } cv; cv.hh = vb;
          w[r] = cv.uu;
          if (s0loc + r >= len) tsum[j] += (float)vb;
        }
        *(ushort4v*)(Vt + (bh * HD_ + j * 16 + l15) * S_ + s0loc) = w;
      }
    }
    if (((int)(rw & (S_ - 1)) + 64) > len)   // wave-uniform: any tail rows
      for (int j = 0; j < 4; j++)
        atomicAdd(&Vtail[bh * HD_ + j * 16 + l15], tsum[j]);
  }
}

// -------------------------------------------------------------- attention ---
// R16-VERIFIED verbatim (measured-best attn).
__global__ __launch_bounds__(256, 4) void attn(
    const _Float16* __restrict__ Qn,
    const _Float16* __restrict__ Kn,
    const unsigned short* __restrict__ Vt,
    const float* __restrict__ Vtail,
    const int* __restrict__ seq_len,
    float* __restrict__ out)
{
  __shared__ _Float16 Ks[2][64 * 32];        // [d-half][key][32]    8 KB
  __shared__ unsigned short Vts[2][64 * 32]; // [key-half][d][32]    8 KB
  __shared__ unsigned int Pt[4][16 * 36];    // per-wave P^T packed  9.2 KB

  int tid = threadIdx.x, lane = tid & 63, wave = tid >> 6;
  int qd = lane >> 4, l15 = lane & 15;
  int b = blockIdx.x;                        // b fastest: len load-balance
  int h = blockIdx.y;
  int q0 = blockIdx.z * 64;
  long bh = (long)b * H_ + h;
  int len = seq_len[b];
  int ntile = (len + 63) >> 6;               // tiles containing any key < len

  int skey = tid >> 2;
  int schunk = (tid & 3) * 8;

  // each wave owns 16 q-rows: q = q0 + wave*16 + l15 (this lane's q)
  f16x8 qf[2];
  {
    const _Float16* qp = Qn + (bh * S_ + q0 + wave * 16 + l15) * HD_;
    qf[0] = *(const f16x8*)(qp + qd * 8);
    qf[1] = *(const f16x8*)(qp + 32 + qd * 8);
  }
  // Vtail per d = t*16 + qd*4 + r -> float4 per t
  f32x4 tv[4];
  for (int t = 0; t < 4; t++)
    tv[t] = *(const f32x4*)(Vtail + bh * HD_ + t * 16 + qd * 4);

  f32x4 o[4] = {};
  float den = 0.f;

  unsigned int* pw = &Pt[wave][0];

  for (int kt = 0; kt < ntile; kt++) {
    GLD16(Kn + (bh * S_ + kt * 64 + skey) * HD_ + schunk,      &Ks[0][0] + tid * 8);
    GLD16(Kn + (bh * S_ + kt * 64 + skey) * HD_ + 32 + schunk, &Ks[1][0] + tid * 8);
    GLD16(Vt + (bh * HD_ + skey) * S_ + kt * 64 + schunk,      &Vts[0][0] + tid * 8);
    GLD16(Vt + (bh * HD_ + skey) * S_ + kt * 64 + 32 + schunk, &Vts[1][0] + tid * 8);
    __syncthreads();

    // ---- S^T tile: sacc[tn][r] = S[k = tn*16+qd*4+r][q = l15] ----
    f32x4 sacc[4] = {};
    for (int tn = 0; tn < 4; tn++) {
      f16x8 kf0 = *(const f16x8*)(&Ks[0][0] + (tn * 16 + l15) * 32 + qd * 8);
      f16x8 kf1 = *(const f16x8*)(&Ks[1][0] + (tn * 16 + l15) * 32 + qd * 8);
      sacc[tn] = __builtin_amdgcn_mfma_f32_16x16x32_f16(kf0, qf[0], sacc[tn], 0, 0, 0);
      sacc[tn] = __builtin_amdgcn_mfma_f32_16x16x32_f16(kf1, qf[1], sacc[tn], 0, 0, 0);
    }

    // ---- exp -> packed bf16 P^T (per-wave LDS; 4 x ds_write_b64) ----
    if (kt * 64 + 64 <= len) {
      for (int tn = 0; tn < 4; tn++) {
        float p0 = __expf(sacc[tn][0]);
        float p1 = __expf(sacc[tn][1]);
        float p2 = __expf(sacc[tn][2]);
        float p3 = __expf(sacc[tn][3]);
        unsigned w0 = pk2bf(p0, p1);
        unsigned w1 = pk2bf(p2, p3);
        // den from bf16-rounded values (matches PV numerator rounding)
        den += (float)(__bf16)p0 + (float)(__bf16)p1
             + (float)(__bf16)p2 + (float)(__bf16)p3;
        *(uint2*)(pw + l15 * 36 + tn * 8 + qd * 2) = make_uint2(w0, w1);
      }
    } else {
      for (int tn = 0; tn < 4; tn++) {
        int kg = kt * 64 + tn * 16 + qd * 4;
        float p[4];
        for (int r = 0; r < 4; r++)
          p[r] = (kg + r < len) ? __expf(sacc[tn][r]) : 0.f;
        unsigned w0 = pk2bf(p[0], p[1]);
        unsigned w1 = pk2bf(p[2], p[3]);
        den += (float)(__bf16)p[0] + (float)(__bf16)p[1]
             + (float)(__bf16)p[2] + (float)(__bf16)p[3];
        *(uint2*)(pw + l15 * 36 + tn * 8 + qd * 2) = make_uint2(w0, w1);
      }
    }

    // ---- O^T += V^T-frag x P-frag ----
    bf16x8 pf0 = *(const bf16x8*)((const unsigned short*)pw + l15 * 72 + qd * 8);
    bf16x8 pf1 = *(const bf16x8*)((const unsigned short*)pw + l15 * 72 + 32 + qd * 8);
    for (int t = 0; t < 4; t++) {
      bf16x8 vf0 = *(const bf16x8*)(&Vts[0][0] + (t * 16 + l15) * 32 + qd * 8);
      bf16x8 vf1 = *(const bf16x8*)(&Vts[1][0] + (t * 16 + l15) * 32 + qd * 8);
      o[t] = __builtin_amdgcn_mfma_f32_16x16x32_bf16(vf0, pf0, o[t], 0, 0, 0);
      o[t] = __builtin_amdgcn_mfma_f32_16x16x32_bf16(vf1, pf1, o[t], 0, 0, 0);
    }
    __syncthreads();
  }

  // ---- epilogue: den reduce over qd groups (q = l15 fixed per lane) ----
  den += __shfl_xor(den, 16, 64);
  den += __shfl_xor(den, 32, 64);
  den += (float)(S_ - len);

  long s = q0 + wave * 16 + l15;
  float* op = out + ((long)b * S_ + s) * D_ + h * 64 + qd * 4;
  for (int t = 0; t < 4; t++) {
    f32x4 r;
    for (int rr = 0; rr < 4; rr++)
      r[rr] = (o[t][rr] + tv[t][rr]) / den;
    *(f32x4*)(op + t * 16) = r;
  }
}

// ----------------------------------------------------------------- launch ---
extern "C" void kernel_launch(void* const* d_in, const int* in_sizes, int n_in,
                              void* d_out, int out_size, void* d_ws, size_t ws_size,
                              hipStream_t stream) {
  const float* x     = (const float*)d_in[0];
  const int*  seq    = (const int*)d_in[1];
  const float* Wq    = (const float*)d_in[2];
  const float* bq    = (const float*)d_in[3];
  const float* Wk    = (const float*)d_in[4];
  const float* bk    = (const float*)d_in[5];
  const float* Wv    = (const float*)d_in[6];
  const float* bv    = (const float*)d_in[7];
  const float* ln_g  = (const float*)d_in[8];
  const float* ln_b  = (const float*)d_in[9];
  float* out = (float*)d_out;

  char* ws = (char*)d_ws;
  _Float16* xh  = (_Float16*)(ws);                          // 8 MB
  _Float16* wqh = (_Float16*)(ws + (8l  << 20));            // 2 MB
  _Float16* wkh = (_Float16*)(ws + (10l << 20));            // 2 MB
  _Float16* wvh = (_Float16*)(ws + (12l << 20));            // 2 MB
  float*    Vtail = (float*)(ws + (14l << 20));             // 16 KB
  _Float16* qh  = (_Float16*)(ws + (16l << 20));            // 8 MB
  _Float16* Qn  = (_Float16*)(ws + (40l << 20));            // 8 MB
  _Float16* Kn  = (_Float16*)(ws + (48l << 20));            // 8 MB
  unsigned short* Vt = (unsigned short*)(ws + (56l << 20)); // 8 MB

  cvt_all<<<7172, 256, 0, stream>>>(x, xh, Wq, wqh, Wk, wkh, Wv, wvh, Vtail);

  dim3 g1(D_ / 128, (B_ * S_) / 128);
  gemm_q_ln<<<g1, 512, 0, stream>>>(xh, wqh, bq, ln_g, ln_b, qh, Qn);

  dim3 g2(D_ / 128, (B_ * S_) / 256, 2);
  gemm_kv_ln<<<g2, 512, 0, stream>>>(qh, wkh, bk, wvh, bv, ln_g, ln_b, seq,
                                     Kn, Vt, Vtail);

  dim3 g4(B_, H_, S_ / 64);
  attn<<<g4, 256, 0, stream>>>(Qn, Kn, Vt, Vtail, seq, out);
}

// Round 13
// 166.655 us; speedup vs baseline: 1.0352x; 1.0352x over previous
//
#include <hip/hip_runtime.h>

#define B_  4
#define S_  1024
#define D_  1024
#define H_  16
#define HD_ 64
#define EPS_ 1e-5f

typedef _Float16 f16x8 __attribute__((ext_vector_type(8)));
typedef _Float16 f16x4 __attribute__((ext_vector_type(4)));
typedef __bf16 bf16x8 __attribute__((ext_vector_type(8)));
typedef float  f32x4  __attribute__((ext_vector_type(4)));
typedef unsigned short ushort4v __attribute__((ext_vector_type(4)));

// async global->LDS, 16B per lane; LDS dest is wave-uniform base + lane*16
#define GLD16(gp, lp) __builtin_amdgcn_global_load_lds( \
    (const __attribute__((address_space(1))) void*)(gp), \
    (__attribute__((address_space(3))) void*)(lp), 16, 0, 0)

// pack two f32 into one u32 of two bf16 (RNE via native cast), low = first
static __device__ __forceinline__ unsigned pk2bf(float a, float b) {
  union { __bf16 h; unsigned short u; } ua, ub;
  ua.h = (__bf16)a; ub.h = (__bf16)b;
  return (unsigned)ua.u | ((unsigned)ub.u << 16);
}

// ---------------------------------------------------------------- convert ---
// R12-VERIFIED verbatim.
__global__ __launch_bounds__(256) void cvt_all(
    const float* __restrict__ x,  _Float16* __restrict__ xh,
    const float* __restrict__ Wq, _Float16* __restrict__ wqh,
    const float* __restrict__ Wk, _Float16* __restrict__ wkh,
    const float* __restrict__ Wv, _Float16* __restrict__ wvh,
    float* __restrict__ Vtail) {
  int bid = blockIdx.x;
  if (bid >= 7168) {                    // 4 blocks zero Vtail (B*H*HD f32)
    int i = (bid - 7168) * 1024 + threadIdx.x * 4;
    *(float4*)(Vtail + i) = make_float4(0.f, 0.f, 0.f, 0.f);
    return;
  }
  const float* src; _Float16* dst; int base;
  if (bid < 4096)      { src = x;  dst = xh;  base = bid; }
  else if (bid < 5120) { src = Wq; dst = wqh; base = bid - 4096; }
  else if (bid < 6144) { src = Wk; dst = wkh; base = bid - 5120; }
  else                 { src = Wv; dst = wvh; base = bid - 6144; }
  int i = base * 1024 + threadIdx.x * 4;
  float4 f = *(const float4*)(src + i);
  f16x4 h;
  h.x = (_Float16)f.x; h.y = (_Float16)f.y; h.z = (_Float16)f.z; h.w = (_Float16)f.w;
  *(f16x4*)(dst + i) = h;
}

// ------------------------------------------- GEMM q + fused LN (128x64) ----
// R19-VERIFIED verbatim (BK=128, XCD swizzle, R12 epilogue). R21 retile
// reverted (1 blk/CU lost inter-block overlap).
__global__ __launch_bounds__(256, 2) void gemm_q_ln(
    const _Float16* __restrict__ A,      // xh [4096,1024]
    const _Float16* __restrict__ Bw,     // wqh [1024,1024]
    const float* __restrict__ bias,      // bq
    const float* __restrict__ ln_g, const float* __restrict__ ln_b,
    _Float16* __restrict__ qh,           // raw q  [4096,1024]
    _Float16* __restrict__ Qn)           // LN'd q, head-major [bh,s,64]
{
  __shared__ _Float16 As[4 * 128 * 32];   // 32 KB  [ks][128 rows][32]
  __shared__ _Float16 Bs[4 * 64 * 32];    // 16 KB  [ks][64 rows][32]

  int tid  = threadIdx.x;
  int lane = tid & 63;
  int wave = tid >> 6;
  int qd = lane >> 4, l15 = lane & 15;

  // ---- XCD-chunked swizzle (flat 0..511; xcd = flat%8 owns by-band) ----
  int flat = blockIdx.x + 16 * blockIdx.y;
  int swz  = (flat & 7) * 64 + (flat >> 3);
  int bx = swz & 15, by = swz >> 4;

  long row0 = (long)by * 128;
  long col0 = (long)bx * 64;

  int r_a = tid >> 2;
  int c_a = (tid & 3) * 8;

  f32x4 acc[2][4] = {};

  for (int kk = 0; kk < D_; kk += 128) {
    for (int ks2 = 0; ks2 < 4; ks2++) {
      GLD16(A  + (row0 + r_a) * D_ + kk + ks2 * 32 + c_a,      As + ks2 * 4096 + tid * 8);
      GLD16(A  + (row0 + 64 + r_a) * D_ + kk + ks2 * 32 + c_a, As + ks2 * 4096 + 2048 + tid * 8);
      GLD16(Bw + (col0 + r_a) * D_ + kk + ks2 * 32 + c_a,      Bs + ks2 * 2048 + tid * 8);
    }
    __syncthreads();

    for (int ks = 0; ks < 4; ks++) {
      f16x8 af[2], bfr[4];
      for (int i = 0; i < 2; i++)
        af[i]  = *(const f16x8*)(As + ks * 4096 + (wave * 32 + i * 16 + l15) * 32 + qd * 8);
      for (int j = 0; j < 4; j++)
        bfr[j] = *(const f16x8*)(Bs + ks * 2048 + (j * 16 + l15) * 32 + qd * 8);
      for (int i = 0; i < 2; i++)
        for (int j = 0; j < 4; j++)
          acc[i][j] = __builtin_amdgcn_mfma_f32_16x16x32_f16(af[i], bfr[j], acc[i][j], 0, 0, 0);
    }
    __syncthreads();
  }

  // ---- fused epilogue: bias + LN over the 64-col head, dual store ----
  int h = bx;                               // block cols == head h
  long rw = row0 + wave * 32;               // wave's first row
  int bb = (int)(rw >> 10);                 // batch (tile within one batch)
  long bh = (long)bb * H_ + h;
  float gv[4], bl[4], bc[4];
  for (int j = 0; j < 4; j++) {
    int d = j * 16 + l15;
    gv[j] = ln_g[d]; bl[j] = ln_b[d]; bc[j] = bias[h * 64 + d];
  }
  for (int i = 0; i < 2; i++) {
    float m4[4], i4[4];
    for (int r = 0; r < 4; r++) {
      float s = 0.f, q = 0.f;
      for (int j = 0; j < 4; j++) {
        float y = acc[i][j][r] + bc[j];
        s += y; q = fmaf(y, y, q);
      }
      for (int off = 1; off < 16; off <<= 1) {
        s += __shfl_xor(s, off, 64);
        q += __shfl_xor(q, off, 64);
      }
      float m = s * (1.f / 64.f);
      m4[r] = m;
      i4[r] = rsqrtf(q * (1.f / 64.f) - m * m + EPS_);
    }
    for (int r = 0; r < 4; r++) {
      long srow = rw + i * 16 + qd * 4 + r;
      long sloc = srow & (S_ - 1);
      for (int j = 0; j < 4; j++) {
        float y = acc[i][j][r] + bc[j];
        qh[srow * D_ + h * 64 + j * 16 + l15] = (_Float16)y;
        Qn[(bh * S_ + sloc) * HD_ + j * 16 + l15] =
            (_Float16)((y - m4[r]) * i4[r] * gv[j] + bl[j]);
      }
    }
  }
}

// ----------------------------------------- GEMM k/v + fused LN (128x128) ---
// R19-VERIFIED verbatim (BK=128, XCD swizzle, R12 epilogues). R20 skip and
// R21 retile both reverted (neutral / regression).
__global__ __launch_bounds__(256, 2) void gemm_kv_ln(
    const _Float16* __restrict__ A,      // qh [4096,1024]
    const _Float16* __restrict__ Bk, const float* __restrict__ bk,
    const _Float16* __restrict__ Bv, const float* __restrict__ bv,
    const float* __restrict__ ln_g, const float* __restrict__ ln_b,
    const int* __restrict__ seq_len,
    _Float16* __restrict__ Kn,           // LN'd k, head-major [bh,s,64]
    unsigned short* __restrict__ Vt,     // LN'd v bf16, transposed [bh,64,S]
    float* __restrict__ Vtail)
{
  __shared__ _Float16 As[4 * 128 * 32];   // 32 KB
  __shared__ _Float16 Bs[4 * 128 * 32];   // 32 KB

  int tid  = threadIdx.x;
  int lane = tid & 63;
  int wave = tid >> 6;
  int wm = wave >> 1, wn = wave & 1;
  int qd = lane >> 4, l15 = lane & 15;

  // ---- XCD-chunked swizzle over flat (bx,by,z), nwg=512, bijective ----
  int flat = blockIdx.x + 8 * blockIdx.y + 256 * blockIdx.z;
  int swz  = (flat & 7) * 64 + (flat >> 3);
  int z    = swz >> 8;
  int rem  = swz & 255;
  int by   = rem >> 3, bx = rem & 7;

  const _Float16* Bm = z ? Bv : Bk;
  const float* bias  = z ? bv : bk;

  long row0 = (long)by * 128;
  long col0 = (long)bx * 128;

  int r_a = tid >> 2;
  int c_a = (tid & 3) * 8;

  f32x4 acc[4][4] = {};

  for (int kk = 0; kk < D_; kk += 128) {
    for (int ks2 = 0; ks2 < 4; ks2++) {
      GLD16(A  + (row0 + r_a) * D_ + kk + ks2 * 32 + c_a,      As + ks2 * 4096 + tid * 8);
      GLD16(A  + (row0 + 64 + r_a) * D_ + kk + ks2 * 32 + c_a, As + ks2 * 4096 + 2048 + tid * 8);
      GLD16(Bm + (col0 + r_a) * D_ + kk + ks2 * 32 + c_a,      Bs + ks2 * 4096 + tid * 8);
      GLD16(Bm + (col0 + 64 + r_a) * D_ + kk + ks2 * 32 + c_a, Bs + ks2 * 4096 + 2048 + tid * 8);
    }
    __syncthreads();

    for (int ks = 0; ks < 4; ks++) {
      f16x8 af[4], bfr[4];
      for (int t = 0; t < 4; t++) {
        af[t]  = *(const f16x8*)(As + ks * 4096 + (wm * 64 + t * 16 + l15) * 32 + qd * 8);
        bfr[t] = *(const f16x8*)(Bs + ks * 4096 + (wn * 64 + t * 16 + l15) * 32 + qd * 8);
      }
      for (int i = 0; i < 4; i++)
        for (int j = 0; j < 4; j++)
          acc[i][j] = __builtin_amdgcn_mfma_f32_16x16x32_f16(af[i], bfr[j], acc[i][j], 0, 0, 0);
    }
    __syncthreads();
  }

  // ---- fused epilogue ----
  int h = bx * 2 + wn;                      // wave's 64-col strip == head h
  long rw = row0 + wm * 64;                 // wave's first row
  int bb = (int)(rw >> 10);
  long bh = (long)bb * H_ + h;
  float gv[4], bl[4], bc[4];
  for (int j = 0; j < 4; j++) {
    int d = j * 16 + l15;
    gv[j] = ln_g[d]; bl[j] = ln_b[d]; bc[j] = bias[h * 64 + d];
  }

  if (z == 0) {
    // ---- k: LN -> f16 Kn head-major ----
    for (int i = 0; i < 4; i++) {
      float m4[4], i4[4];
      for (int r = 0; r < 4; r++) {
        float s = 0.f, q = 0.f;
        for (int j = 0; j < 4; j++) {
          float y = acc[i][j][r] + bc[j];
          s += y; q = fmaf(y, y, q);
        }
        for (int off = 1; off < 16; off <<= 1) {
          s += __shfl_xor(s, off, 64);
          q += __shfl_xor(q, off, 64);
        }
        float m = s * (1.f / 64.f);
        m4[r] = m;
        i4[r] = rsqrtf(q * (1.f / 64.f) - m * m + EPS_);
      }
      for (int r = 0; r < 4; r++) {
        long sloc = (rw + i * 16 + qd * 4 + r) & (S_ - 1);
        for (int j = 0; j < 4; j++) {
          float y = acc[i][j][r] + bc[j];
          Kn[(bh * S_ + sloc) * HD_ + j * 16 + l15] =
              (_Float16)((y - m4[r]) * i4[r] * gv[j] + bl[j]);
        }
      }
    }
  } else {
    // ---- v: LN -> bf16 Vt transposed + Vtail tail sums ----
    int len = seq_len[bb];
    float tsum[4] = {0.f, 0.f, 0.f, 0.f};
    for (int i = 0; i < 4; i++) {
      float m4[4], i4[4];
      for (int r = 0; r < 4; r++) {
        float s = 0.f, q = 0.f;
        for (int j = 0; j < 4; j++) {
          float y = acc[i][j][r] + bc[j];
          s += y; q = fmaf(y, y, q);
        }
        for (int off = 1; off < 16; off <<= 1) {
          s += __shfl_xor(s, off, 64);
          q += __shfl_xor(q, off, 64);
        }
        float m = s * (1.f / 64.f);
        m4[r] = m;
        i4[r] = rsqrtf(q * (1.f / 64.f) - m * m + EPS_);
      }
      int s0loc = (int)((rw + i * 16 + qd * 4) & (S_ - 1));
      for (int j = 0; j < 4; j++) {
        ushort4v w;
        for (int r = 0; r < 4; r++) {
          float y = acc[i][j][r] + bc[j];
          float vo = (y - m4[r]) * i4[r] * gv[j] + bl[j];
          __bf16 vb = (__bf16)vo;
          union { __bf16 hh; unsigned short uu; } cv; cv.hh = vb;
          w[r] = cv.uu;
          if (s0loc + r >= len) tsum[j] += (float)vb;
        }
        *(ushort4v*)(Vt + (bh * HD_ + j * 16 + l15) * S_ + s0loc) = w;
      }
    }
    if (((int)(rw & (S_ - 1)) + 64) > len)   // wave-uniform: any tail rows
      for (int j = 0; j < 4; j++)
        atomicAdd(&Vtail[bh * HD_ + j * 16 + l15], tsum[j]);
  }
}

// -------------------------------------------------------------- attention ---
// R22: 32 q-rows per WAVE (mt=2 sub-tiles of the R16-verified structure).
// Per-tile LDS-read volume is proportional to 1/(q-rows per wave) -- each
// wave reads the full 8KB K-tile + 8KB V-tile regardless of q-count, so
// doubling q/wave halves LDS read traffic per q (K/V fragments in registers
// are reused across both mt MFMAs). Blocks: 128 threads (2 waves, 64 q),
// grid unchanged at 1024; LDS 25.2 KB -> 6 blocks/CU (12 waves/CU).
// All fragment layouts / P-path / epilogue formulas are R16-verified; only
// mt indexing added and staging re-indexed for 128 threads (same linear
// p -> (key,chunk) map as the 256-thread version).
__global__ __launch_bounds__(128, 3) void attn(
    const _Float16* __restrict__ Qn,
    const _Float16* __restrict__ Kn,
    const unsigned short* __restrict__ Vt,
    const float* __restrict__ Vtail,
    const int* __restrict__ seq_len,
    float* __restrict__ out)
{
  __shared__ _Float16 Ks[2][64 * 32];        // [d-half][key][32]    8 KB
  __shared__ unsigned short Vts[2][64 * 32]; // [key-half][d][32]    8 KB
  __shared__ unsigned int Pt[2][32 * 36];    // per-wave P^T packed  9.2 KB

  int tid = threadIdx.x, lane = tid & 63, wave = tid >> 6;  // wave 0..1
  int qd = lane >> 4, l15 = lane & 15;
  int b = blockIdx.x;                        // b fastest: len load-balance
  int h = blockIdx.y;
  int q0 = blockIdx.z * 64;
  long bh = (long)b * H_ + h;
  int len = seq_len[b];
  int ntile = (len + 63) >> 6;               // tiles containing any key < len

  // each wave owns 32 q-rows: q = q0 + wave*32 + mt*16 + l15
  f16x8 qf[2][2];
  for (int mt = 0; mt < 2; mt++) {
    const _Float16* qp = Qn + (bh * S_ + q0 + wave * 32 + mt * 16 + l15) * HD_;
    qf[mt][0] = *(const f16x8*)(qp + qd * 8);
    qf[mt][1] = *(const f16x8*)(qp + 32 + qd * 8);
  }
  // Vtail per d = t*16 + qd*4 + r -> float4 per t
  f32x4 tv[4];
  for (int t = 0; t < 4; t++)
    tv[t] = *(const f32x4*)(Vtail + bh * HD_ + t * 16 + qd * 4);

  f32x4 o[2][4] = {};
  float den[2] = {0.f, 0.f};

  unsigned int* pw = &Pt[wave][0];

  for (int kt = 0; kt < ntile; kt++) {
    // stage K (both d-halves) + V^T (both key-halves); 128 threads x 2 slots
    // p in [0,256): key/d-row = p>>2, 16B chunk = (p&3)*8 f16. Dest = linear
    // p*16B satisfies the wave-uniform-base + lane*16 rule for both waves.
    for (int p = tid; p < 256; p += 128) {
      GLD16(Kn + (bh * S_ + kt * 64 + (p >> 2)) * HD_ + (p & 3) * 8,      &Ks[0][0] + p * 8);
      GLD16(Kn + (bh * S_ + kt * 64 + (p >> 2)) * HD_ + 32 + (p & 3) * 8, &Ks[1][0] + p * 8);
      GLD16(Vt + (bh * HD_ + (p >> 2)) * S_ + kt * 64 + (p & 3) * 8,      &Vts[0][0] + p * 8);
      GLD16(Vt + (bh * HD_ + (p >> 2)) * S_ + kt * 64 + 32 + (p & 3) * 8, &Vts[1][0] + p * 8);
    }
    __syncthreads();

    // ---- S^T: sacc[mt][tn][r] = S[k = tn*16+qd*4+r][q(mt,l15)] ----
    // K fragments loaded ONCE, reused across both mt (the LDS saving).
    f32x4 sacc[2][4] = {};
    for (int tn = 0; tn < 4; tn++) {
      f16x8 kf0 = *(const f16x8*)(&Ks[0][0] + (tn * 16 + l15) * 32 + qd * 8);
      f16x8 kf1 = *(const f16x8*)(&Ks[1][0] + (tn * 16 + l15) * 32 + qd * 8);
      for (int mt = 0; mt < 2; mt++) {
        sacc[mt][tn] = __builtin_amdgcn_mfma_f32_16x16x32_f16(kf0, qf[mt][0], sacc[mt][tn], 0, 0, 0);
        sacc[mt][tn] = __builtin_amdgcn_mfma_f32_16x16x32_f16(kf1, qf[mt][1], sacc[mt][tn], 0, 0, 0);
      }
    }

    // ---- exp -> packed bf16 P^T (per-wave LDS; 4 x ds_write_b64 per mt) ----
    if (kt * 64 + 64 <= len) {
      for (int mt = 0; mt < 2; mt++)
        for (int tn = 0; tn < 4; tn++) {
          float p0 = __expf(sacc[mt][tn][0]);
          float p1 = __expf(sacc[mt][tn][1]);
          float p2 = __expf(sacc[mt][tn][2]);
          float p3 = __expf(sacc[mt][tn][3]);
          unsigned w0 = pk2bf(p0, p1);
          unsigned w1 = pk2bf(p2, p3);
          den[mt] += (float)(__bf16)p0 + (float)(__bf16)p1
                   + (float)(__bf16)p2 + (float)(__bf16)p3;
          *(uint2*)(pw + (mt * 16 + l15) * 36 + tn * 8 + qd * 2) = make_uint2(w0, w1);
        }
    } else {
      for (int mt = 0; mt < 2; mt++)
        for (int tn = 0; tn < 4; tn++) {
          int kg = kt * 64 + tn * 16 + qd * 4;
          float p[4];
          for (int r = 0; r < 4; r++)
            p[r] = (kg + r < len) ? __expf(sacc[mt][tn][r]) : 0.f;
          unsigned w0 = pk2bf(p[0], p[1]);
          unsigned w1 = pk2bf(p[2], p[3]);
          den[mt] += (float)(__bf16)p[0] + (float)(__bf16)p[1]
                   + (float)(__bf16)p[2] + (float)(__bf16)p[3];
          *(uint2*)(pw + (mt * 16 + l15) * 36 + tn * 8 + qd * 2) = make_uint2(w0, w1);
        }
    }

    // ---- O^T += V^T-frag x P-frag; V fragments reused across both mt ----
    bf16x8 pf[2][2];
    for (int mt = 0; mt < 2; mt++) {
      pf[mt][0] = *(const bf16x8*)((const unsigned short*)pw + (mt * 16 + l15) * 72 + qd * 8);
      pf[mt][1] = *(const bf16x8*)((const unsigned short*)pw + (mt * 16 + l15) * 72 + 32 + qd * 8);
    }
    for (int t = 0; t < 4; t++) {
      bf16x8 vf0 = *(const bf16x8*)(&Vts[0][0] + (t * 16 + l15) * 32 + qd * 8);
      bf16x8 vf1 = *(const bf16x8*)(&Vts[1][0] + (t * 16 + l15) * 32 + qd * 8);
      for (int mt = 0; mt < 2; mt++) {
        o[mt][t] = __builtin_amdgcn_mfma_f32_16x16x32_bf16(vf0, pf[mt][0], o[mt][t], 0, 0, 0);
        o[mt][t] = __builtin_amdgcn_mfma_f32_16x16x32_bf16(vf1, pf[mt][1], o[mt][t], 0, 0, 0);
      }
    }
    __syncthreads();
  }

  // ---- epilogue: den reduce over qd groups (q fixed per lane per mt) ----
  float tden = (float)(S_ - len);
  for (int mt = 0; mt < 2; mt++) {
    den[mt] += __shfl_xor(den[mt], 16, 64);
    den[mt] += __shfl_xor(den[mt], 32, 64);
    den[mt] += tden;
  }

  for (int mt = 0; mt < 2; mt++) {
    long s = q0 + wave * 32 + mt * 16 + l15;
    float* op = out + ((long)b * S_ + s) * D_ + h * 64 + qd * 4;
    for (int t = 0; t < 4; t++) {
      f32x4 r;
      for (int rr = 0; rr < 4; rr++)
        r[rr] = (o[mt][t][rr] + tv[t][rr]) / den[mt];
      *(f32x4*)(op + t * 16) = r;
    }
  }
}

// ----------------------------------------------------------------- launch ---
extern "C" void kernel_launch(void* const* d_in, const int* in_sizes, int n_in,
                              void* d_out, int out_size, void* d_ws, size_t ws_size,
                              hipStream_t stream) {
  const float* x     = (const float*)d_in[0];
  const int*  seq    = (const int*)d_in[1];
  const float* Wq    = (const float*)d_in[2];
  const float* bq    = (const float*)d_in[3];
  const float* Wk    = (const float*)d_in[4];
  const float* bk    = (const float*)d_in[5];
  const float* Wv    = (const float*)d_in[6];
  const float* bv    = (const float*)d_in[7];
  const float* ln_g  = (const float*)d_in[8];
  const float* ln_b  = (const float*)d_in[9];
  float* out = (float*)d_out;

  char* ws = (char*)d_ws;
  _Float16* xh  = (_Float16*)(ws);                          // 8 MB
  _Float16* wqh = (_Float16*)(ws + (8l  << 20));            // 2 MB
  _Float16* wkh = (_Float16*)(ws + (10l << 20));            // 2 MB
  _Float16* wvh = (_Float16*)(ws + (12l << 20));            // 2 MB
  float*    Vtail = (float*)(ws + (14l << 20));             // 16 KB
  _Float16* qh  = (_Float16*)(ws + (16l << 20));            // 8 MB
  _Float16* Qn  = (_Float16*)(ws + (40l << 20));            // 8 MB
  _Float16* Kn  = (_Float16*)(ws + (48l << 20));            // 8 MB
  unsigned short* Vt = (unsigned short*)(ws + (56l << 20)); // 8 MB

  cvt_all<<<7172, 256, 0, stream>>>(x, xh, Wq, wqh, Wk, wkh, Wv, wvh, Vtail);

  dim3 g1(D_ / 64, (B_ * S_) / 128);
  gemm_q_ln<<<g1, 256, 0, stream>>>(xh, wqh, bq, ln_g, ln_b, qh, Qn);

  dim3 g2(D_ / 128, (B_ * S_) / 128, 2);
  gemm_kv_ln<<<g2, 256, 0, stream>>>(qh, wkh, bk, wvh, bv, ln_g, ln_b, seq,
                                     Kn, Vt, Vtail);

  dim3 g4(B_, H_, S_ / 64);
  attn<<<g4, 128, 0, stream>>>(Qn, Kn, Vt, Vtail, seq, out);
}

// Round 14
// 161.312 us; speedup vs baseline: 1.0694x; 1.0331x over previous
//
#include <hip/hip_runtime.h>

#define B_  4
#define S_  1024
#define D_  1024
#define H_  16
#define HD_ 64
#define EPS_ 1e-5f

typedef _Float16 f16x8 __attribute__((ext_vector_type(8)));
typedef _Float16 f16x4 __attribute__((ext_vector_type(4)));
typedef __bf16 bf16x8 __attribute__((ext_vector_type(8)));
typedef float  f32x4  __attribute__((ext_vector_type(4)));
typedef unsigned short ushort4v __attribute__((ext_vector_type(4)));

// async global->LDS, 16B per lane; LDS dest is wave-uniform base + lane*16
#define GLD16(gp, lp) __builtin_amdgcn_global_load_lds( \
    (const __attribute__((address_space(1))) void*)(gp), \
    (__attribute__((address_space(3))) void*)(lp), 16, 0, 0)

// pack two f32 into one u32 of two bf16 (RNE via native cast), low = first
static __device__ __forceinline__ unsigned pk2bf(float a, float b) {
  union { __bf16 h; unsigned short u; } ua, ub;
  ua.h = (__bf16)a; ub.h = (__bf16)b;
  return (unsigned)ua.u | ((unsigned)ub.u << 16);
}

// ---------------------------------------------------------------- convert ---
// R12-VERIFIED verbatim.
__global__ __launch_bounds__(256) void cvt_all(
    const float* __restrict__ x,  _Float16* __restrict__ xh,
    const float* __restrict__ Wq, _Float16* __restrict__ wqh,
    const float* __restrict__ Wk, _Float16* __restrict__ wkh,
    const float* __restrict__ Wv, _Float16* __restrict__ wvh,
    float* __restrict__ Vtail) {
  int bid = blockIdx.x;
  if (bid >= 7168) {                    // 4 blocks zero Vtail (B*H*HD f32)
    int i = (bid - 7168) * 1024 + threadIdx.x * 4;
    *(float4*)(Vtail + i) = make_float4(0.f, 0.f, 0.f, 0.f);
    return;
  }
  const float* src; _Float16* dst; int base;
  if (bid < 4096)      { src = x;  dst = xh;  base = bid; }
  else if (bid < 5120) { src = Wq; dst = wqh; base = bid - 4096; }
  else if (bid < 6144) { src = Wk; dst = wkh; base = bid - 5120; }
  else                 { src = Wv; dst = wvh; base = bid - 6144; }
  int i = base * 1024 + threadIdx.x * 4;
  float4 f = *(const float4*)(src + i);
  f16x4 h;
  h.x = (_Float16)f.x; h.y = (_Float16)f.y; h.z = (_Float16)f.z; h.w = (_Float16)f.w;
  *(f16x4*)(dst + i) = h;
}

// ------------------------------------------- GEMM q + fused LN (128x64) ----
// R19-VERIFIED verbatim (BK=128, XCD swizzle, R12 epilogue).
__global__ __launch_bounds__(256, 2) void gemm_q_ln(
    const _Float16* __restrict__ A,      // xh [4096,1024]
    const _Float16* __restrict__ Bw,     // wqh [1024,1024]
    const float* __restrict__ bias,      // bq
    const float* __restrict__ ln_g, const float* __restrict__ ln_b,
    _Float16* __restrict__ qh,           // raw q  [4096,1024]
    _Float16* __restrict__ Qn)           // LN'd q, head-major [bh,s,64]
{
  __shared__ _Float16 As[4 * 128 * 32];   // 32 KB  [ks][128 rows][32]
  __shared__ _Float16 Bs[4 * 64 * 32];    // 16 KB  [ks][64 rows][32]

  int tid  = threadIdx.x;
  int lane = tid & 63;
  int wave = tid >> 6;
  int qd = lane >> 4, l15 = lane & 15;

  // ---- XCD-chunked swizzle (flat 0..511; xcd = flat%8 owns by-band) ----
  int flat = blockIdx.x + 16 * blockIdx.y;
  int swz  = (flat & 7) * 64 + (flat >> 3);
  int bx = swz & 15, by = swz >> 4;

  long row0 = (long)by * 128;
  long col0 = (long)bx * 64;

  int r_a = tid >> 2;
  int c_a = (tid & 3) * 8;

  f32x4 acc[2][4] = {};

  for (int kk = 0; kk < D_; kk += 128) {
    for (int ks2 = 0; ks2 < 4; ks2++) {
      GLD16(A  + (row0 + r_a) * D_ + kk + ks2 * 32 + c_a,      As + ks2 * 4096 + tid * 8);
      GLD16(A  + (row0 + 64 + r_a) * D_ + kk + ks2 * 32 + c_a, As + ks2 * 4096 + 2048 + tid * 8);
      GLD16(Bw + (col0 + r_a) * D_ + kk + ks2 * 32 + c_a,      Bs + ks2 * 2048 + tid * 8);
    }
    __syncthreads();

    for (int ks = 0; ks < 4; ks++) {
      f16x8 af[2], bfr[4];
      for (int i = 0; i < 2; i++)
        af[i]  = *(const f16x8*)(As + ks * 4096 + (wave * 32 + i * 16 + l15) * 32 + qd * 8);
      for (int j = 0; j < 4; j++)
        bfr[j] = *(const f16x8*)(Bs + ks * 2048 + (j * 16 + l15) * 32 + qd * 8);
      for (int i = 0; i < 2; i++)
        for (int j = 0; j < 4; j++)
          acc[i][j] = __builtin_amdgcn_mfma_f32_16x16x32_f16(af[i], bfr[j], acc[i][j], 0, 0, 0);
    }
    __syncthreads();
  }

  // ---- fused epilogue: bias + LN over the 64-col head, dual store ----
  int h = bx;                               // block cols == head h
  long rw = row0 + wave * 32;               // wave's first row
  int bb = (int)(rw >> 10);                 // batch (tile within one batch)
  long bh = (long)bb * H_ + h;
  float gv[4], bl[4], bc[4];
  for (int j = 0; j < 4; j++) {
    int d = j * 16 + l15;
    gv[j] = ln_g[d]; bl[j] = ln_b[d]; bc[j] = bias[h * 64 + d];
  }
  for (int i = 0; i < 2; i++) {
    float m4[4], i4[4];
    for (int r = 0; r < 4; r++) {
      float s = 0.f, q = 0.f;
      for (int j = 0; j < 4; j++) {
        float y = acc[i][j][r] + bc[j];
        s += y; q = fmaf(y, y, q);
      }
      for (int off = 1; off < 16; off <<= 1) {
        s += __shfl_xor(s, off, 64);
        q += __shfl_xor(q, off, 64);
      }
      float m = s * (1.f / 64.f);
      m4[r] = m;
      i4[r] = rsqrtf(q * (1.f / 64.f) - m * m + EPS_);
    }
    for (int r = 0; r < 4; r++) {
      long srow = rw + i * 16 + qd * 4 + r;
      long sloc = srow & (S_ - 1);
      for (int j = 0; j < 4; j++) {
        float y = acc[i][j][r] + bc[j];
        qh[srow * D_ + h * 64 + j * 16 + l15] = (_Float16)y;
        Qn[(bh * S_ + sloc) * HD_ + j * 16 + l15] =
            (_Float16)((y - m4[r]) * i4[r] * gv[j] + bl[j]);
      }
    }
  }
}

// ----------------------------------------- GEMM k/v + fused LN (128x128) ---
// R19-VERIFIED verbatim (BK=128, XCD swizzle, R12 epilogues).
__global__ __launch_bounds__(256, 2) void gemm_kv_ln(
    const _Float16* __restrict__ A,      // qh [4096,1024]
    const _Float16* __restrict__ Bk, const float* __restrict__ bk,
    const _Float16* __restrict__ Bv, const float* __restrict__ bv,
    const float* __restrict__ ln_g, const float* __restrict__ ln_b,
    const int* __restrict__ seq_len,
    _Float16* __restrict__ Kn,           // LN'd k, head-major [bh,s,64]
    unsigned short* __restrict__ Vt,     // LN'd v bf16, transposed [bh,64,S]
    float* __restrict__ Vtail)
{
  __shared__ _Float16 As[4 * 128 * 32];   // 32 KB
  __shared__ _Float16 Bs[4 * 128 * 32];   // 32 KB

  int tid  = threadIdx.x;
  int lane = tid & 63;
  int wave = tid >> 6;
  int wm = wave >> 1, wn = wave & 1;
  int qd = lane >> 4, l15 = lane & 15;

  // ---- XCD-chunked swizzle over flat (bx,by,z), nwg=512, bijective ----
  int flat = blockIdx.x + 8 * blockIdx.y + 256 * blockIdx.z;
  int swz  = (flat & 7) * 64 + (flat >> 3);
  int z    = swz >> 8;
  int rem  = swz & 255;
  int by   = rem >> 3, bx = rem & 7;

  const _Float16* Bm = z ? Bv : Bk;
  const float* bias  = z ? bv : bk;

  long row0 = (long)by * 128;
  long col0 = (long)bx * 128;

  int r_a = tid >> 2;
  int c_a = (tid & 3) * 8;

  f32x4 acc[4][4] = {};

  for (int kk = 0; kk < D_; kk += 128) {
    for (int ks2 = 0; ks2 < 4; ks2++) {
      GLD16(A  + (row0 + r_a) * D_ + kk + ks2 * 32 + c_a,      As + ks2 * 4096 + tid * 8);
      GLD16(A  + (row0 + 64 + r_a) * D_ + kk + ks2 * 32 + c_a, As + ks2 * 4096 + 2048 + tid * 8);
      GLD16(Bm + (col0 + r_a) * D_ + kk + ks2 * 32 + c_a,      Bs + ks2 * 4096 + tid * 8);
      GLD16(Bm + (col0 + 64 + r_a) * D_ + kk + ks2 * 32 + c_a, Bs + ks2 * 4096 + 2048 + tid * 8);
    }
    __syncthreads();

    for (int ks = 0; ks < 4; ks++) {
      f16x8 af[4], bfr[4];
      for (int t = 0; t < 4; t++) {
        af[t]  = *(const f16x8*)(As + ks * 4096 + (wm * 64 + t * 16 + l15) * 32 + qd * 8);
        bfr[t] = *(const f16x8*)(Bs + ks * 4096 + (wn * 64 + t * 16 + l15) * 32 + qd * 8);
      }
      for (int i = 0; i < 4; i++)
        for (int j = 0; j < 4; j++)
          acc[i][j] = __builtin_amdgcn_mfma_f32_16x16x32_f16(af[i], bfr[j], acc[i][j], 0, 0, 0);
    }
    __syncthreads();
  }

  // ---- fused epilogue ----
  int h = bx * 2 + wn;                      // wave's 64-col strip == head h
  long rw = row0 + wm * 64;                 // wave's first row
  int bb = (int)(rw >> 10);
  long bh = (long)bb * H_ + h;
  float gv[4], bl[4], bc[4];
  for (int j = 0; j < 4; j++) {
    int d = j * 16 + l15;
    gv[j] = ln_g[d]; bl[j] = ln_b[d]; bc[j] = bias[h * 64 + d];
  }

  if (z == 0) {
    // ---- k: LN -> f16 Kn head-major ----
    for (int i = 0; i < 4; i++) {
      float m4[4], i4[4];
      for (int r = 0; r < 4; r++) {
        float s = 0.f, q = 0.f;
        for (int j = 0; j < 4; j++) {
          float y = acc[i][j][r] + bc[j];
          s += y; q = fmaf(y, y, q);
        }
        for (int off = 1; off < 16; off <<= 1) {
          s += __shfl_xor(s, off, 64);
          q += __shfl_xor(q, off, 64);
        }
        float m = s * (1.f / 64.f);
        m4[r] = m;
        i4[r] = rsqrtf(q * (1.f / 64.f) - m * m + EPS_);
      }
      for (int r = 0; r < 4; r++) {
        long sloc = (rw + i * 16 + qd * 4 + r) & (S_ - 1);
        for (int j = 0; j < 4; j++) {
          float y = acc[i][j][r] + bc[j];
          Kn[(bh * S_ + sloc) * HD_ + j * 16 + l15] =
              (_Float16)((y - m4[r]) * i4[r] * gv[j] + bl[j]);
        }
      }
    }
  } else {
    // ---- v: LN -> bf16 Vt transposed + Vtail tail sums ----
    int len = seq_len[bb];
    float tsum[4] = {0.f, 0.f, 0.f, 0.f};
    for (int i = 0; i < 4; i++) {
      float m4[4], i4[4];
      for (int r = 0; r < 4; r++) {
        float s = 0.f, q = 0.f;
        for (int j = 0; j < 4; j++) {
          float y = acc[i][j][r] + bc[j];
          s += y; q = fmaf(y, y, q);
        }
        for (int off = 1; off < 16; off <<= 1) {
          s += __shfl_xor(s, off, 64);
          q += __shfl_xor(q, off, 64);
        }
        float m = s * (1.f / 64.f);
        m4[r] = m;
        i4[r] = rsqrtf(q * (1.f / 64.f) - m * m + EPS_);
      }
      int s0loc = (int)((rw + i * 16 + qd * 4) & (S_ - 1));
      for (int j = 0; j < 4; j++) {
        ushort4v w;
        for (int r = 0; r < 4; r++) {
          float y = acc[i][j][r] + bc[j];
          float vo = (y - m4[r]) * i4[r] * gv[j] + bl[j];
          __bf16 vb = (__bf16)vo;
          union { __bf16 hh; unsigned short uu; } cv; cv.hh = vb;
          w[r] = cv.uu;
          if (s0loc + r >= len) tsum[j] += (float)vb;
        }
        *(ushort4v*)(Vt + (bh * HD_ + j * 16 + l15) * S_ + s0loc) = w;
      }
    }
    if (((int)(rw & (S_ - 1)) + 64) > len)   // wave-uniform: any tail rows
      for (int j = 0; j < 4; j++)
        atomicAdd(&Vtail[bh * HD_ + j * 16 + l15], tsum[j]);
  }
}

// -------------------------------------------------------------- attention ---
// R16-VERIFIED structure + R23: T5 s_setprio(1/0) around both MFMA clusters.
// m191 precedent: +4-7% on attn where blocks on a CU are INDEPENDENT (ours:
// 4 blocks/CU, no inter-block barriers, seq_len spread = phase diversity).
// Null on barrier-lockstep GEMMs (m190) -- so applied to attn only.
__global__ __launch_bounds__(256, 4) void attn(
    const _Float16* __restrict__ Qn,
    const _Float16* __restrict__ Kn,
    const unsigned short* __restrict__ Vt,
    const float* __restrict__ Vtail,
    const int* __restrict__ seq_len,
    float* __restrict__ out)
{
  __shared__ _Float16 Ks[2][64 * 32];        // [d-half][key][32]    8 KB
  __shared__ unsigned short Vts[2][64 * 32]; // [key-half][d][32]    8 KB
  __shared__ unsigned int Pt[4][16 * 36];    // per-wave P^T packed  9.2 KB

  int tid = threadIdx.x, lane = tid & 63, wave = tid >> 6;
  int qd = lane >> 4, l15 = lane & 15;
  int b = blockIdx.x;                        // b fastest: len load-balance
  int h = blockIdx.y;
  int q0 = blockIdx.z * 64;
  long bh = (long)b * H_ + h;
  int len = seq_len[b];
  int ntile = (len + 63) >> 6;               // tiles containing any key < len

  int skey = tid >> 2;
  int schunk = (tid & 3) * 8;

  // each wave owns 16 q-rows: q = q0 + wave*16 + l15 (this lane's q)
  f16x8 qf[2];
  {
    const _Float16* qp = Qn + (bh * S_ + q0 + wave * 16 + l15) * HD_;
    qf[0] = *(const f16x8*)(qp + qd * 8);
    qf[1] = *(const f16x8*)(qp + 32 + qd * 8);
  }
  // Vtail per d = t*16 + qd*4 + r -> float4 per t
  f32x4 tv[4];
  for (int t = 0; t < 4; t++)
    tv[t] = *(const f32x4*)(Vtail + bh * HD_ + t * 16 + qd * 4);

  f32x4 o[4] = {};
  float den = 0.f;

  unsigned int* pw = &Pt[wave][0];

  for (int kt = 0; kt < ntile; kt++) {
    GLD16(Kn + (bh * S_ + kt * 64 + skey) * HD_ + schunk,      &Ks[0][0] + tid * 8);
    GLD16(Kn + (bh * S_ + kt * 64 + skey) * HD_ + 32 + schunk, &Ks[1][0] + tid * 8);
    GLD16(Vt + (bh * HD_ + skey) * S_ + kt * 64 + schunk,      &Vts[0][0] + tid * 8);
    GLD16(Vt + (bh * HD_ + skey) * S_ + kt * 64 + 32 + schunk, &Vts[1][0] + tid * 8);
    __syncthreads();

    // ---- S^T tile: sacc[tn][r] = S[k = tn*16+qd*4+r][q = l15] ----
    f32x4 sacc[4] = {};
    __builtin_amdgcn_s_setprio(1);
    for (int tn = 0; tn < 4; tn++) {
      f16x8 kf0 = *(const f16x8*)(&Ks[0][0] + (tn * 16 + l15) * 32 + qd * 8);
      f16x8 kf1 = *(const f16x8*)(&Ks[1][0] + (tn * 16 + l15) * 32 + qd * 8);
      sacc[tn] = __builtin_amdgcn_mfma_f32_16x16x32_f16(kf0, qf[0], sacc[tn], 0, 0, 0);
      sacc[tn] = __builtin_amdgcn_mfma_f32_16x16x32_f16(kf1, qf[1], sacc[tn], 0, 0, 0);
    }
    __builtin_amdgcn_s_setprio(0);

    // ---- exp -> packed bf16 P^T (per-wave LDS; 4 x ds_write_b64) ----
    if (kt * 64 + 64 <= len) {
      for (int tn = 0; tn < 4; tn++) {
        float p0 = __expf(sacc[tn][0]);
        float p1 = __expf(sacc[tn][1]);
        float p2 = __expf(sacc[tn][2]);
        float p3 = __expf(sacc[tn][3]);
        unsigned w0 = pk2bf(p0, p1);
        unsigned w1 = pk2bf(p2, p3);
        // den from bf16-rounded values (matches PV numerator rounding)
        den += (float)(__bf16)p0 + (float)(__bf16)p1
             + (float)(__bf16)p2 + (float)(__bf16)p3;
        *(uint2*)(pw + l15 * 36 + tn * 8 + qd * 2) = make_uint2(w0, w1);
      }
    } else {
      for (int tn = 0; tn < 4; tn++) {
        int kg = kt * 64 + tn * 16 + qd * 4;
        float p[4];
        for (int r = 0; r < 4; r++)
          p[r] = (kg + r < len) ? __expf(sacc[tn][r]) : 0.f;
        unsigned w0 = pk2bf(p[0], p[1]);
        unsigned w1 = pk2bf(p[2], p[3]);
        den += (float)(__bf16)p[0] + (float)(__bf16)p[1]
             + (float)(__bf16)p[2] + (float)(__bf16)p[3];
        *(uint2*)(pw + l15 * 36 + tn * 8 + qd * 2) = make_uint2(w0, w1);
      }
    }

    // ---- O^T += V^T-frag x P-frag ----
    bf16x8 pf0 = *(const bf16x8*)((const unsigned short*)pw + l15 * 72 + qd * 8);
    bf16x8 pf1 = *(const bf16x8*)((const unsigned short*)pw + l15 * 72 + 32 + qd * 8);
    __builtin_amdgcn_s_setprio(1);
    for (int t = 0; t < 4; t++) {
      bf16x8 vf0 = *(const bf16x8*)(&Vts[0][0] + (t * 16 + l15) * 32 + qd * 8);
      bf16x8 vf1 = *(const bf16x8*)(&Vts[1][0] + (t * 16 + l15) * 32 + qd * 8);
      o[t] = __builtin_amdgcn_mfma_f32_16x16x32_bf16(vf0, pf0, o[t], 0, 0, 0);
      o[t] = __builtin_amdgcn_mfma_f32_16x16x32_bf16(vf1, pf1, o[t], 0, 0, 0);
    }
    __builtin_amdgcn_s_setprio(0);
    __syncthreads();
  }

  // ---- epilogue: den reduce over qd groups (q = l15 fixed per lane) ----
  den += __shfl_xor(den, 16, 64);
  den += __shfl_xor(den, 32, 64);
  den += (float)(S_ - len);

  long s = q0 + wave * 16 + l15;
  float* op = out + ((long)b * S_ + s) * D_ + h * 64 + qd * 4;
  for (int t = 0; t < 4; t++) {
    f32x4 r;
    for (int rr = 0; rr < 4; rr++)
      r[rr] = (o[t][rr] + tv[t][rr]) / den;
    *(f32x4*)(op + t * 16) = r;
  }
}

// ----------------------------------------------------------------- launch ---
extern "C" void kernel_launch(void* const* d_in, const int* in_sizes, int n_in,
                              void* d_out, int out_size, void* d_ws, size_t ws_size,
                              hipStream_t stream) {
  const float* x     = (const float*)d_in[0];
  const int*  seq    = (const int*)d_in[1];
  const float* Wq    = (const float*)d_in[2];
  const float* bq    = (const float*)d_in[3];
  const float* Wk    = (const float*)d_in[4];
  const float* bk    = (const float*)d_in[5];
  const float* Wv    = (const float*)d_in[6];
  const float* bv    = (const float*)d_in[7];
  const float* ln_g  = (const float*)d_in[8];
  const float* ln_b  = (const float*)d_in[9];
  float* out = (float*)d_out;

  char* ws = (char*)d_ws;
  _Float16* xh  = (_Float16*)(ws);                          // 8 MB
  _Float16* wqh = (_Float16*)(ws + (8l  << 20));            // 2 MB
  _Float16* wkh = (_Float16*)(ws + (10l << 20));            // 2 MB
  _Float16* wvh = (_Float16*)(ws + (12l << 20));            // 2 MB
  float*    Vtail = (float*)(ws + (14l << 20));             // 16 KB
  _Float16* qh  = (_Float16*)(ws + (16l << 20));            // 8 MB
  _Float16* Qn  = (_Float16*)(ws + (40l << 20));            // 8 MB
  _Float16* Kn  = (_Float16*)(ws + (48l << 20));            // 8 MB
  unsigned short* Vt = (unsigned short*)(ws + (56l << 20)); // 8 MB

  cvt_all<<<7172, 256, 0, stream>>>(x, xh, Wq, wqh, Wk, wkh, Wv, wvh, Vtail);

  dim3 g1(D_ / 64, (B_ * S_) / 128);
  gemm_q_ln<<<g1, 256, 0, stream>>>(xh, wqh, bq, ln_g, ln_b, qh, Qn);

  dim3 g2(D_ / 128, (B_ * S_) / 128, 2);
  gemm_kv_ln<<<g2, 256, 0, stream>>>(qh, wkh, bk, wvh, bv, ln_g, ln_b, seq,
                                     Kn, Vt, Vtail);

  dim3 g4(B_, H_, S_ / 64);
  attn<<<g4, 256, 0, stream>>>(Qn, Kn, Vt, Vtail, seq, out);
}